// Round 1
// baseline (104.949 us; speedup 1.0000x reference)
//
#include <hip/hip_runtime.h>

// MeanAggregator: out[b,:] = mean_{s<25} emb[neigh[b,s], :], emb fp32 [100000,128].
// Memory-bound gather. 32 lanes x float4 cover one 128-dim row; 8 rows/block.

constexpr int EMB_DIM     = 128;
constexpr int NUM_SAMPLE  = 25;
constexpr int ROWS_PER_BLOCK = 8;   // 8 rows * 32 lanes = 256 threads

__global__ __launch_bounds__(256)
void mean_agg_kernel(const float* __restrict__ emb,
                     const int*   __restrict__ neigh,
                     float*       __restrict__ out,
                     int batch)
{
    const int row  = blockIdx.x * ROWS_PER_BLOCK + (threadIdx.x >> 5);
    const int lane = threadIdx.x & 31;          // 32 lanes per row, float4 each
    if (row >= batch) return;

    const int* nrow = neigh + (size_t)row * NUM_SAMPLE;

    float4 acc = make_float4(0.f, 0.f, 0.f, 0.f);
    #pragma unroll
    for (int s = 0; s < NUM_SAMPLE; ++s) {
        const int idx = nrow[s];                // broadcast load (same addr all 32 lanes)
        const float4* src = reinterpret_cast<const float4*>(emb + (size_t)idx * EMB_DIM);
        float4 v = src[lane];                   // coalesced 512B row read
        acc.x += v.x; acc.y += v.y; acc.z += v.z; acc.w += v.w;
    }

    constexpr float inv = 1.0f / NUM_SAMPLE;
    acc.x *= inv; acc.y *= inv; acc.z *= inv; acc.w *= inv;

    reinterpret_cast<float4*>(out + (size_t)row * EMB_DIM)[lane] = acc;
}

extern "C" void kernel_launch(void* const* d_in, const int* in_sizes, int n_in,
                              void* d_out, int out_size, void* d_ws, size_t ws_size,
                              hipStream_t stream) {
    const float* emb   = (const float*)d_in[0];
    const int*   neigh = (const int*)d_in[1];
    float*       out   = (float*)d_out;

    const int batch = in_sizes[1] / NUM_SAMPLE;   // 16384
    const int grid  = (batch + ROWS_PER_BLOCK - 1) / ROWS_PER_BLOCK;

    mean_agg_kernel<<<grid, 256, 0, stream>>>(emb, neigh, out, batch);
}

// Round 2
// 103.201 us; speedup vs baseline: 1.0169x; 1.0169x over previous
//
#include <hip/hip_runtime.h>

// MeanAggregator: out[b,:] = mean_{s<25} emb[neigh[b,s], :], emb fp32 [100000,128].
// Latency-bound random gather. 32 lanes x float4 cover one 128-dim row (512B);
// 8 rows per 256-thread block. Indices are fetched with ONE coalesced load per
// 32-lane group and broadcast via __shfl (ds_bpermute, lgkmcnt path) so the 25
// row-gathers carry no interleaved vmcnt dependencies -> max MLP.

constexpr int EMB_DIM        = 128;
constexpr int NUM_SAMPLE     = 25;
constexpr int ROWS_PER_BLOCK = 8;   // 8 rows * 32 lanes = 256 threads

__global__ __launch_bounds__(256)
void mean_agg_kernel(const float* __restrict__ emb,
                     const int*   __restrict__ neigh,
                     float*       __restrict__ out,
                     int batch)
{
    const int row  = blockIdx.x * ROWS_PER_BLOCK + (threadIdx.x >> 5);
    const int lane = threadIdx.x & 31;          // lane within the 32-lane row group
    if (row >= batch) return;

    const int* nrow = neigh + (size_t)row * NUM_SAMPLE;

    // One coalesced index load per group: lanes 0..24 each grab one index.
    int my_idx = (lane < NUM_SAMPLE) ? nrow[lane] : 0;

    float4 acc = make_float4(0.f, 0.f, 0.f, 0.f);
    #pragma unroll
    for (int s = 0; s < NUM_SAMPLE; ++s) {
        // Broadcast sample s's index within this 32-lane group (VALU/LDS path,
        // does not enter the vmcnt queue).
        const int idx = __shfl(my_idx, s, 32);
        const float4* src = reinterpret_cast<const float4*>(emb + (size_t)idx * EMB_DIM);
        float4 v = src[lane];                   // coalesced 512B row read
        acc.x += v.x; acc.y += v.y; acc.z += v.z; acc.w += v.w;
    }

    constexpr float inv = 1.0f / NUM_SAMPLE;
    acc.x *= inv; acc.y *= inv; acc.z *= inv; acc.w *= inv;

    reinterpret_cast<float4*>(out + (size_t)row * EMB_DIM)[lane] = acc;
}

extern "C" void kernel_launch(void* const* d_in, const int* in_sizes, int n_in,
                              void* d_out, int out_size, void* d_ws, size_t ws_size,
                              hipStream_t stream) {
    const float* emb   = (const float*)d_in[0];
    const int*   neigh = (const int*)d_in[1];
    float*       out   = (float*)d_out;

    const int batch = in_sizes[1] / NUM_SAMPLE;   // 16384
    const int grid  = (batch + ROWS_PER_BLOCK - 1) / ROWS_PER_BLOCK;

    mean_agg_kernel<<<grid, 256, 0, stream>>>(emb, neigh, out, batch);
}